// Round 8
// baseline (327.037 us; speedup 1.0000x reference)
//
#include <hip/hip_runtime.h>

#define H_ 448
#define W_ 96
#define CIN_ 128
#define HW_ (H_*W_)   // 43008

__device__ __forceinline__ float lrelu(float v){ return v > 0.0f ? v : 0.01f*v; }

// Counting sort of 96 pixels by class (NC classes). All threads must call.
template<int NC>
__device__ __forceinline__ void sort_by_class(const unsigned char* s_cls, short* s_perm,
                                              int* s_cnt, int* s_off, int t)
{
    if (t < NC){
        int c = 0;
        for (int p = 0; p < 96; p++) if (s_cls[p] == (unsigned char)t) c++;
        s_cnt[t] = c;
    }
    __syncthreads();
    if (t == 0){
        int a = 0;
        for (int c = 0; c < NC; c++){ s_off[c] = a; a += s_cnt[c]; }
    }
    __syncthreads();
    if (t < NC){
        int o = s_off[t];
        for (int p = 0; p < 96; p++) if (s_cls[p] == (unsigned char)t) s_perm[o++] = (short)p;
    }
    __syncthreads();
}

// Build 4-pixel single-class chunks from the sorted runs. t==0 serial (tiny).
template<int NC>
__device__ __forceinline__ void build_chunks(const int* s_cnt, const int* s_off,
                                             int* s_chunk, int* s_nch, int t)
{
    if (t == 0){
        int n = 0;
        for (int c = 0; c < NC; c++){
            const int cnt = s_cnt[c];
            for (int b = 0; b < cnt; b += 4) s_chunk[n++] = (c << 16) | (s_off[c] + b);
        }
        *s_nch = n;
    }
    __syncthreads();
}

__global__ __launch_bounds__(384, 4)
void cls3_fused(const float* __restrict__ X,
                const float* __restrict__ w1_0, const float* __restrict__ b1_0,
                const float* __restrict__ w1_1, const float* __restrict__ b1_1,
                const float* __restrict__ w1_2, const float* __restrict__ b1_2,
                const float* __restrict__ w2_0, const float* __restrict__ b2_0,
                const float* __restrict__ w2_1, const float* __restrict__ b2_1,
                const float* __restrict__ w2_2, const float* __restrict__ b2_2,
                const float* __restrict__ w3_0, const float* __restrict__ b3_0,
                const float* __restrict__ w3_1, const float* __restrict__ b3_1,
                const float* __restrict__ w3_2, const float* __restrict__ b3_2,
                int* __restrict__ out)
{
    __shared__ float s_w0[4096];     // stage-1 w1_0[h]  [o=32][i=128]
    __shared__ float s_w1[1024];     // stage-1 w1_1[h]  [o=32][i=32]
    __shared__ float s_w2[256];      // stage-1 w1_2[h]  [o=8][i=32]
    __shared__ float s_A[96*36];     // activations ping (stage1 stride 33; stage2/3 stride 36)
    __shared__ float s_B[96*36];     // activations pong
    __shared__ unsigned char s_cls[96];     // stage-1 routing
    __shared__ unsigned char s_cls2[96];    // stage-2 routing
    __shared__ short s_perm[96];
    __shared__ int   s_raw[96];
    __shared__ int   s_cnt[64];
    __shared__ int   s_off[64];
    __shared__ int   s_chunk[96];
    __shared__ int   s_nch;

    const int h  = blockIdx.x;
    const int t  = threadIdx.x;

    // ================= stage 1 (w=pixel, s=0..3 owns 8 channels) =================
    {
        const int w  = t % 96;
        const int s  = t / 96;
        const int hw = h*96 + w;

        const float* g0 = w1_0 + (size_t)h*4096;
        for (int j = t; j < 4096; j += 384) s_w0[j] = g0[j];
        const float* g1 = w1_1 + (size_t)h*1024;
        for (int j = t; j < 1024; j += 384) s_w1[j] = g1[j];
        const float* g2 = w1_2 + (size_t)h*256;
        for (int j = t; j < 256; j += 384) s_w2[j] = g2[j];
        __syncthreads();

        // L0: 128 -> 32
        {
            float acc[8];
            const float* bp = b1_0 + h*32 + s*8;
            #pragma unroll
            for (int k=0;k<8;k++) acc[k] = bp[k];
            #pragma unroll 4
            for (int i4=0;i4<32;i4++){
                const float x0 = X[(size_t)(4*i4+0)*HW_ + hw];
                const float x1 = X[(size_t)(4*i4+1)*HW_ + hw];
                const float x2 = X[(size_t)(4*i4+2)*HW_ + hw];
                const float x3 = X[(size_t)(4*i4+3)*HW_ + hw];
                #pragma unroll
                for (int k=0;k<8;k++){
                    const float4 q = *(const float4*)&s_w0[(s*8+k)*128 + 4*i4];
                    acc[k] += x0*q.x; acc[k] += x1*q.y; acc[k] += x2*q.z; acc[k] += x3*q.w;
                }
            }
            #pragma unroll
            for (int k=0;k<8;k++) s_A[w*33 + s*8 + k] = lrelu(acc[k]);
        }
        __syncthreads();

        // L1: 32 -> 32
        {
            float acc[8];
            const float* bp = b1_1 + h*32 + s*8;
            #pragma unroll
            for (int k=0;k<8;k++) acc[k] = bp[k];
            #pragma unroll
            for (int i4=0;i4<8;i4++){
                const float x0 = s_A[w*33 + 4*i4+0];
                const float x1 = s_A[w*33 + 4*i4+1];
                const float x2 = s_A[w*33 + 4*i4+2];
                const float x3 = s_A[w*33 + 4*i4+3];
                #pragma unroll
                for (int k=0;k<8;k++){
                    const float4 q = *(const float4*)&s_w1[(s*8+k)*32 + 4*i4];
                    acc[k] += x0*q.x; acc[k] += x1*q.y; acc[k] += x2*q.z; acc[k] += x3*q.w;
                }
            }
            #pragma unroll
            for (int k=0;k<8;k++) s_B[w*33 + s*8 + k] = lrelu(acc[k]);
        }
        __syncthreads();

        // L2: 32 -> 8 (each s owns 2 outputs)
        {
            float acc[2];
            const float* bp = b1_2 + h*8 + s*2;
            acc[0] = bp[0]; acc[1] = bp[1];
            #pragma unroll
            for (int i4=0;i4<8;i4++){
                const float x0 = s_B[w*33 + 4*i4+0];
                const float x1 = s_B[w*33 + 4*i4+1];
                const float x2 = s_B[w*33 + 4*i4+2];
                const float x3 = s_B[w*33 + 4*i4+3];
                #pragma unroll
                for (int k=0;k<2;k++){
                    const float4 q = *(const float4*)&s_w2[(s*2+k)*32 + 4*i4];
                    acc[k] += x0*q.x; acc[k] += x1*q.y; acc[k] += x2*q.z; acc[k] += x3*q.w;
                }
            }
            s_A[w*33 + s*2 + 0] = acc[0];
            s_A[w*33 + s*2 + 1] = acc[1];
        }
        __syncthreads();

        if (t < 96){
            const float* sc = &s_A[t*33];
            float best = sc[0]; int bi = 0;
            #pragma unroll
            for (int k=1;k<8;k++){ const float v = sc[k]; if (v > best){ best = v; bi = k; } }
            s_cls[t] = (unsigned char)bi;
        }
        __syncthreads();
    }

    const int g = t >> 4;   // 16-lane group id, 0..23
    const int l = t & 15;   // lane within group; owns channels {2l,2l+1} (L0/L1), channel l (L2)

    // ================= stage 2: sort + uniform 4-pixel chunks =================
    sort_by_class<8>(s_cls, s_perm, s_cnt, s_off, t);
    build_chunks<8>(s_cnt, s_off, s_chunk, &s_nch, t);
    {
        const int nch = s_nch;
        for (int ck = g; ck < nch; ck += 24){
            const int info = s_chunk[ck];
            const int c    = info >> 16;
            const int base = info & 0xffff;
            const int rend = s_off[c] + s_cnt[c];
            int idx[4]; bool val[4];
            #pragma unroll
            for (int k=0;k<4;k++){
                int s0 = base + k;
                val[k] = s0 < rend;
                if (!val[k]) s0 = rend - 1;
                idx[k] = s_perm[s0];
            }
            const long e = (long)h*8 + c;
            const float* Xb = X + h*96;

            // L0: 128 -> 32 — one weight row load serves 4 pixels
            const float2 bv0 = *(const float2*)&b2_0[e*32 + 2*l];
            float2 a0=bv0, a1=bv0, a2=bv0, a3=bv0;
            const float* W0 = w2_0 + e*4096 + 2*l;
            #pragma unroll 8
            for (int i=0;i<128;i++){
                const float2 wq = *(const float2*)&W0[i*32];
                const float x0 = Xb[(size_t)i*HW_ + idx[0]];
                const float x1 = Xb[(size_t)i*HW_ + idx[1]];
                const float x2 = Xb[(size_t)i*HW_ + idx[2]];
                const float x3 = Xb[(size_t)i*HW_ + idx[3]];
                a0.x += x0*wq.x; a0.y += x0*wq.y;
                a1.x += x1*wq.x; a1.y += x1*wq.y;
                a2.x += x2*wq.x; a2.y += x2*wq.y;
                a3.x += x3*wq.x; a3.y += x3*wq.y;
            }
            if (val[0]) *(float2*)&s_A[idx[0]*36 + 2*l] = make_float2(lrelu(a0.x), lrelu(a0.y));
            if (val[1]) *(float2*)&s_A[idx[1]*36 + 2*l] = make_float2(lrelu(a1.x), lrelu(a1.y));
            if (val[2]) *(float2*)&s_A[idx[2]*36 + 2*l] = make_float2(lrelu(a2.x), lrelu(a2.y));
            if (val[3]) *(float2*)&s_A[idx[3]*36 + 2*l] = make_float2(lrelu(a3.x), lrelu(a3.y));

            // L1: 32 -> 32 (group-local through LDS; same wave, no barrier)
            const float2 bv1 = *(const float2*)&b2_1[e*32 + 2*l];
            float2 c0=bv1, c1=bv1, c2=bv1, c3=bv1;
            const float* W1 = w2_1 + e*1024 + 2*l;
            #pragma unroll 8
            for (int i=0;i<32;i++){
                const float2 wq = *(const float2*)&W1[i*32];
                const float x0 = s_A[idx[0]*36 + i];
                const float x1 = s_A[idx[1]*36 + i];
                const float x2 = s_A[idx[2]*36 + i];
                const float x3 = s_A[idx[3]*36 + i];
                c0.x += x0*wq.x; c0.y += x0*wq.y;
                c1.x += x1*wq.x; c1.y += x1*wq.y;
                c2.x += x2*wq.x; c2.y += x2*wq.y;
                c3.x += x3*wq.x; c3.y += x3*wq.y;
            }
            if (val[0]) *(float2*)&s_B[idx[0]*36 + 2*l] = make_float2(lrelu(c0.x), lrelu(c0.y));
            if (val[1]) *(float2*)&s_B[idx[1]*36 + 2*l] = make_float2(lrelu(c1.x), lrelu(c1.y));
            if (val[2]) *(float2*)&s_B[idx[2]*36 + 2*l] = make_float2(lrelu(c2.x), lrelu(c2.y));
            if (val[3]) *(float2*)&s_B[idx[3]*36 + 2*l] = make_float2(lrelu(c3.x), lrelu(c3.y));

            // L2: 32 -> 16 (lane owns channel l)
            float d0, d1, d2, d3;
            d0 = d1 = d2 = d3 = b2_2[e*16 + l];
            const float* W2 = w2_2 + e*512 + l;
            #pragma unroll 8
            for (int i=0;i<32;i++){
                const float wq = W2[i*16];
                d0 += s_B[idx[0]*36 + i]*wq;
                d1 += s_B[idx[1]*36 + i]*wq;
                d2 += s_B[idx[2]*36 + i]*wq;
                d3 += s_B[idx[3]*36 + i]*wq;
            }
            float dd[4] = { d0, d1, d2, d3 };
            #pragma unroll
            for (int k=0;k<4;k++){
                float best = dd[k]; int bi = l;
                #pragma unroll
                for (int off=1; off<16; off<<=1){
                    const float ob = __shfl_xor(best, off, 64);
                    const int  obi = __shfl_xor(bi,  off, 64);
                    if (ob > best || (ob == best && obi < bi)){ best = ob; bi = obi; }
                }
                if (l == 0 && val[k]){
                    const int raw = c*8 + bi - 4;
                    s_raw[idx[k]]  = raw;
                    s_cls2[idx[k]] = (unsigned char)(raw < 0 ? 0 : (raw > 63 ? 63 : raw));
                }
            }
        }
    }
    __syncthreads();

    // ================= stage 3: sort + uniform 4-pixel chunks =================
    sort_by_class<64>(s_cls2, s_perm, s_cnt, s_off, t);
    build_chunks<64>(s_cnt, s_off, s_chunk, &s_nch, t);
    {
        const int nch = s_nch;
        for (int ck = g; ck < nch; ck += 24){
            const int info = s_chunk[ck];
            const int c    = info >> 16;
            const int base = info & 0xffff;
            const int rend = s_off[c] + s_cnt[c];
            int idx[4]; bool val[4];
            #pragma unroll
            for (int k=0;k<4;k++){
                int s0 = base + k;
                val[k] = s0 < rend;
                if (!val[k]) s0 = rend - 1;
                idx[k] = s_perm[s0];
            }
            const long e = (long)h*64 + c;
            const float* Xb = X + h*96;

            const float2 bv0 = *(const float2*)&b3_0[e*32 + 2*l];
            float2 a0=bv0, a1=bv0, a2=bv0, a3=bv0;
            const float* W0 = w3_0 + e*4096 + 2*l;
            #pragma unroll 8
            for (int i=0;i<128;i++){
                const float2 wq = *(const float2*)&W0[i*32];
                const float x0 = Xb[(size_t)i*HW_ + idx[0]];
                const float x1 = Xb[(size_t)i*HW_ + idx[1]];
                const float x2 = Xb[(size_t)i*HW_ + idx[2]];
                const float x3 = Xb[(size_t)i*HW_ + idx[3]];
                a0.x += x0*wq.x; a0.y += x0*wq.y;
                a1.x += x1*wq.x; a1.y += x1*wq.y;
                a2.x += x2*wq.x; a2.y += x2*wq.y;
                a3.x += x3*wq.x; a3.y += x3*wq.y;
            }
            if (val[0]) *(float2*)&s_A[idx[0]*36 + 2*l] = make_float2(lrelu(a0.x), lrelu(a0.y));
            if (val[1]) *(float2*)&s_A[idx[1]*36 + 2*l] = make_float2(lrelu(a1.x), lrelu(a1.y));
            if (val[2]) *(float2*)&s_A[idx[2]*36 + 2*l] = make_float2(lrelu(a2.x), lrelu(a2.y));
            if (val[3]) *(float2*)&s_A[idx[3]*36 + 2*l] = make_float2(lrelu(a3.x), lrelu(a3.y));

            const float2 bv1 = *(const float2*)&b3_1[e*32 + 2*l];
            float2 c0=bv1, c1=bv1, c2=bv1, c3=bv1;
            const float* W1 = w3_1 + e*1024 + 2*l;
            #pragma unroll 8
            for (int i=0;i<32;i++){
                const float2 wq = *(const float2*)&W1[i*32];
                const float x0 = s_A[idx[0]*36 + i];
                const float x1 = s_A[idx[1]*36 + i];
                const float x2 = s_A[idx[2]*36 + i];
                const float x3 = s_A[idx[3]*36 + i];
                c0.x += x0*wq.x; c0.y += x0*wq.y;
                c1.x += x1*wq.x; c1.y += x1*wq.y;
                c2.x += x2*wq.x; c2.y += x2*wq.y;
                c3.x += x3*wq.x; c3.y += x3*wq.y;
            }
            if (val[0]) *(float2*)&s_B[idx[0]*36 + 2*l] = make_float2(lrelu(c0.x), lrelu(c0.y));
            if (val[1]) *(float2*)&s_B[idx[1]*36 + 2*l] = make_float2(lrelu(c1.x), lrelu(c1.y));
            if (val[2]) *(float2*)&s_B[idx[2]*36 + 2*l] = make_float2(lrelu(c2.x), lrelu(c2.y));
            if (val[3]) *(float2*)&s_B[idx[3]*36 + 2*l] = make_float2(lrelu(c3.x), lrelu(c3.y));

            float d0, d1, d2, d3;
            d0 = d1 = d2 = d3 = b3_2[e*16 + l];
            const float* W2 = w3_2 + e*512 + l;
            #pragma unroll 8
            for (int i=0;i<32;i++){
                const float wq = W2[i*16];
                d0 += s_B[idx[0]*36 + i]*wq;
                d1 += s_B[idx[1]*36 + i]*wq;
                d2 += s_B[idx[2]*36 + i]*wq;
                d3 += s_B[idx[3]*36 + i]*wq;
            }
            float dd[4] = { d0, d1, d2, d3 };
            #pragma unroll
            for (int k=0;k<4;k++){
                float best = dd[k]; int bi = l;
                #pragma unroll
                for (int off=1; off<16; off<<=1){
                    const float ob = __shfl_xor(best, off, 64);
                    const int  obi = __shfl_xor(bi,  off, 64);
                    if (ob > best || (ob == best && obi < bi)){ best = ob; bi = obi; }
                }
                if (l == 0 && val[k]){
                    int v = s_raw[idx[k]]*8 + bi - 4;
                    v = v < 0 ? 0 : (v > 511 ? 511 : v);
                    out[h*96 + idx[k]] = v;
                }
            }
        }
    }
}

extern "C" void kernel_launch(void* const* d_in, const int* in_sizes, int n_in,
                              void* d_out, int out_size, void* d_ws, size_t ws_size,
                              hipStream_t stream) {
    const float* X    = (const float*)d_in[0];
    const float* w1_0 = (const float*)d_in[1];
    const float* b1_0 = (const float*)d_in[2];
    const float* w1_1 = (const float*)d_in[3];
    const float* b1_1 = (const float*)d_in[4];
    const float* w1_2 = (const float*)d_in[5];
    const float* b1_2 = (const float*)d_in[6];
    const float* w2_0 = (const float*)d_in[7];
    const float* b2_0 = (const float*)d_in[8];
    const float* w2_1 = (const float*)d_in[9];
    const float* b2_1 = (const float*)d_in[10];
    const float* w2_2 = (const float*)d_in[11];
    const float* b2_2 = (const float*)d_in[12];
    const float* w3_0 = (const float*)d_in[13];
    const float* b3_0 = (const float*)d_in[14];
    const float* w3_1 = (const float*)d_in[15];
    const float* b3_1 = (const float*)d_in[16];
    const float* w3_2 = (const float*)d_in[17];
    const float* b3_2 = (const float*)d_in[18];
    int* out = (int*)d_out;

    cls3_fused<<<H_, 384, 0, stream>>>(X,
        w1_0, b1_0, w1_1, b1_1, w1_2, b1_2,
        w2_0, b2_0, w2_1, b2_1, w2_2, b2_2,
        w3_0, b3_0, w3_1, b3_1, w3_2, b3_2,
        out);
}